// Round 3
// baseline (683.657 us; speedup 1.0000x reference)
//
#include <hip/hip_runtime.h>
#include <math.h>
#include <stdint.h>

// Match numpy float32 semantics exactly in branchy geometry (no FMA contraction).
#pragma clang fp contract(off)

#define SUB 16   // sub-blocks per (stage,gt) in argmin

struct WS {
  double sums[8];                  // 0 cls, 1 gl_i, 2 oob_i, 3 gl_r, 4 oob_r
  unsigned long long packed[128];  // (dd_bits<<32)|idx per (a*64+k)
  int lo[8], hi[8];                // per-level [start,end) point ranges
  float gcx[64], gcy[64], gw[64], gh[64];
  int glvl[64];
  int pos_cnt[2];
  int pos_j[2][64];
  int pos_g[2][64];
  int pos_lab[2][64];
};

// ---------------- init ----------------
__global__ void k_init(WS* ws) {
  int t = threadIdx.x;
  if (t < 8) { ws->sums[t] = 0.0; ws->lo[t] = 0x7fffffff; ws->hi[t] = 0; }
  if (t < 128) ws->packed[t] = ~0ULL;
  if (t < 2) ws->pos_cnt[t] = 0;
}

// ---------------- per-level index bounds ----------------
__global__ void k_bounds(const float* __restrict__ stridev, int N, WS* ws) {
  __shared__ int slo[8], shi[8];
  int t = threadIdx.x;
  if (t < 8) { slo[t] = 0x7fffffff; shi[t] = 0; }
  __syncthreads();
  int i = blockIdx.x * blockDim.x + t;
  if (i < N) {
    int l = (int)log2f(stridev[i]);
    l = l < 0 ? 0 : (l > 7 ? 7 : l);
    atomicMin(&slo[l], i);
    atomicMax(&shi[l], i + 1);
  }
  __syncthreads();
  if (t < 8 && shi[t] > 0) {
    atomicMin(&ws->lo[t], slo[t]);
    atomicMax(&ws->hi[t], shi[t]);
  }
}

// ---------------- gt preprocessing ----------------
__global__ void k_gtprep(const float* __restrict__ gob, int K, WS* ws) {
  __shared__ int lmin, lmax;
  int k = threadIdx.x;
  if (k == 0) {
    int a = 7, b = 0;
    for (int l = 0; l < 8; l++)
      if (ws->lo[l] < ws->hi[l]) { if (l < a) a = l; if (l > b) b = l; }
    lmin = a; lmax = b;
  }
  __syncthreads();
  if (k < K && k < 64) {
    const float* g = gob + k * 8;
    float x0 = g[0], x1 = g[2], x2 = g[4], x3 = g[6];
    float y0 = g[1], y1 = g[3], y2 = g[5], y3 = g[7];
    float xmin = fminf(fminf(x0, x1), fminf(x2, x3));
    float xmax = fmaxf(fmaxf(x0, x1), fmaxf(x2, x3));
    float ymin = fminf(fminf(y0, y1), fminf(y2, y3));
    float ymax = fmaxf(fmaxf(y0, y1), fmaxf(y2, y3));
    float w = fmaxf(xmax - xmin, 1e-6f);
    float h = fmaxf(ymax - ymin, 1e-6f);
    ws->gcx[k] = (xmin + xmax) * 0.5f;
    ws->gcy[k] = (ymin + ymax) * 0.5f;
    ws->gw[k] = w; ws->gh[k] = h;
    int gl = (int)((log2f(w * 0.25f) + log2f(h * 0.25f)) * 0.5f);  // trunc (positive)
    gl = gl < lmin ? lmin : (gl > lmax ? lmax : gl);
    ws->glvl[k] = gl;
  }
}

// ---------------- per-(stage,gt) argmin ----------------
__global__ void __launch_bounds__(256) k_argmin(const float* __restrict__ rpi,
                                                const float* __restrict__ rpr,
                                                const float* __restrict__ stridev,
                                                int N, int K, WS* ws) {
  int b = blockIdx.x;
  int s = b % SUB;
  int ak = b / SUB;
  int a = ak / K;
  int k = ak % K;
  int L = ws->glvl[k];
  int lo = ws->lo[L], hi = ws->hi[L];
  float cx = ws->gcx[k], cy = ws->gcy[k], w = ws->gw[k], h = ws->gh[k];
  const float* rep = a ? rpr : rpi;
  unsigned long long best = ~0ULL;
  for (int i = lo + s * 256 + (int)threadIdx.x; i < hi; i += SUB * 256) {
    int l = (int)log2f(stridev[i]);
    if (l != L) continue;
    const float2 p = *(const float2*)(rep + (size_t)i * 18 + 8);
    float dx = (p.x - cx) / w, dy = (p.y - cy) / h;
    float dd = sqrtf(dx * dx + dy * dy);
    unsigned long long pk = ((unsigned long long)__float_as_uint(dd) << 32) | (unsigned)i;
    if (pk < best) best = pk;
  }
  __shared__ unsigned long long sb[256];
  sb[threadIdx.x] = best;
  __syncthreads();
  for (int off = 128; off > 0; off >>= 1) {
    if ((int)threadIdx.x < off) {
      unsigned long long o = sb[threadIdx.x + off];
      if (o < sb[threadIdx.x]) sb[threadIdx.x] = o;
    }
    __syncthreads();
  }
  if (threadIdx.x == 0) atomicMin(&ws->packed[a * 64 + k], sb[0]);
}

// ---------------- cls base loss: sum_i (lse_i - x_i[0]) ----------------
__global__ void __launch_bounds__(256) k_cls(const float* __restrict__ cls, int N, WS* ws) {
  __shared__ double sd[256];
  int t = threadIdx.x;
  int i = blockIdx.x * 256 + t;
  double v = 0.0;
  if (i < N) {
    const float4* r = (const float4*)(cls + (size_t)i * 16);
    float4 q0 = r[0], q1 = r[1], q2 = r[2], q3 = r[3];
    float x[16] = {q0.x, q0.y, q0.z, q0.w, q1.x, q1.y, q1.z, q1.w,
                   q2.x, q2.y, q2.z, q2.w, q3.x, q3.y, q3.z, q3.w};
    float m = x[0];
    for (int j = 1; j < 16; j++) m = fmaxf(m, x[j]);
    float ssum = 0.f;
    for (int j = 0; j < 16; j++) ssum += expf(x[j] - m);
    v = (double)(logf(ssum) + m - x[0]);
  }
  sd[t] = v;
  __syncthreads();
  for (int off = 128; off > 0; off >>= 1) {
    if (t < off) sd[t] += sd[t + off];
    __syncthreads();
  }
  if (t == 0) atomicAdd(&ws->sums[0], sd[0]);
}

// ---------------- serial resolution of the scan ----------------
__global__ void k_resolve(const float* __restrict__ cls, const int* __restrict__ glab,
                          int N, int K, WS* ws) {
  if (threadIdx.x != 0 || blockIdx.x != 0) return;
  for (int a = 0; a < 2; a++) {
    int ej[64]; int eind[64]; float ed[64]; int ne = 0;
    for (int k = 0; k < K && k < 64; k++) {
      unsigned long long p = ws->packed[a * 64 + k];
      if (p == ~0ULL) continue;
      float md = __uint_as_float((unsigned)(p >> 32));
      int j = (int)(unsigned)(p & 0xffffffffu);
      int f = -1;
      for (int t = 0; t < ne; t++) if (ej[t] == j) { f = t; break; }
      float cur = (f >= 0) ? ed[f] : INFINITY;
      if (md < cur) {
        if (f < 0) { f = ne++; ej[f] = j; }
        eind[f] = k + 1; ed[f] = md;
      }
    }
    ws->pos_cnt[a] = ne;
    double corr = 0.0;
    for (int t = 0; t < ne; t++) {
      ws->pos_j[a][t] = ej[t];
      int g = eind[t] - 1;
      ws->pos_g[a][t] = g;
      int lab = glab[g];
      ws->pos_lab[a][t] = lab;
      if (a == 1) corr += (double)(cls[(size_t)ej[t] * 16 + 0] - cls[(size_t)ej[t] * 16 + lab]);
    }
    if (a == 1) ws->sums[0] += corr;  // stream-ordered after k_cls
  }
}

// ---------------- per-point geometry ----------------
__device__ void stable_argsort(const float* key, int n, int* order) {
  for (int i = 0; i < n; i++) order[i] = i;
  for (int i = 1; i < n; i++) {
    int oi = order[i];
    float ki = key[oi];
    int j = i - 1;
    while (j >= 0 && key[order[j]] > ki) { order[j + 1] = order[j]; j--; }
    order[j + 1] = oi;
  }
}

__device__ float shoelace16(const float* Vx, const float* Vy, int c) {
  float s = 0.f;
  for (int i = 0; i < 16; i++) {
    if (i < c) {
      int nx = (i + 1 < c) ? (i + 1 < 16 ? i + 1 : 15) : 0;  // JAX OOB-gather clamps
      s += Vx[i] * Vy[nx] - Vx[nx] * Vy[i];
    }
  }
  return 0.5f * fabsf(s);
}

// returns hull count; fills V[0..15] (sorted-hull-first then rest, zeros beyond n)
__device__ int convex_hull(const float* Px, const float* Py, int n, float* Vx, float* Vy) {
  bool hull[16];
  int cnt = 0;
  for (int i = 0; i < n; i++) {
    bool h = false;
    for (int j = 0; j < n && !h; j++) {
      if (j == i) continue;
      float dx = Px[j] - Px[i], dy = Py[j] - Py[i];
      float m = INFINITY;
      for (int k = 0; k < n; k++) {
        float cr = dx * (Py[k] - Py[i]) - dy * (Px[k] - Px[i]);
        m = fminf(m, cr);
      }
      if (m >= -1e-6f) h = true;
    }
    hull[i] = h;
    if (h) cnt++;
  }
  float cenx = 0.f, ceny = 0.f;
  for (int i = 0; i < n; i++) if (hull[i]) { cenx += Px[i]; ceny += Py[i]; }
  float dn = (float)(cnt > 1 ? cnt : 1);
  cenx /= dn; ceny /= dn;
  float key[16];
  for (int i = 0; i < n; i++)
    key[i] = hull[i] ? atan2f(Py[i] - ceny, Px[i] - cenx) : INFINITY;
  int order[16];
  stable_argsort(key, n, order);
  for (int t = 0; t < 16; t++) { Vx[t] = 0.f; Vy[t] = 0.f; }
  for (int t = 0; t < n; t++) { Vx[t] = Px[order[t]]; Vy[t] = Py[order[t]]; }
  return cnt;
}

// Sutherland-Hodgman one-edge clip, exactly mirroring reference _clip
__device__ int clip16(float* Vx, float* Vy, int c, float ax, float ay, float bx, float by) {
  float ex = bx - ax, ey = by - ay;
  float ox[16], oy[16];
  for (int t = 0; t < 16; t++) { ox[t] = 0.f; oy[t] = 0.f; }
  int pos = 0;
  for (int i = 0; i < 16; i++) {
    bool active = i < c;
    int nxt = (i + 1 < c) ? (i + 1 < 16 ? i + 1 : 15) : 0;  // JAX OOB-gather clamps
    float nx_ = Vx[nxt], ny_ = Vy[nxt];
    float s_cur = ex * (Vy[i] - ay) - ey * (Vx[i] - ax);
    float s_nxt = ex * (ny_ - ay) - ey * (nx_ - ax);
    bool in_cur = s_cur >= 0.f, in_nxt = s_nxt >= 0.f;
    float den = s_cur - s_nxt;
    bool safe = fabsf(den) > 1e-9f;
    float t_ = safe ? s_cur / den : 0.f;
    float ix = Vx[i] + t_ * (nx_ - Vx[i]);
    float iy = Vy[i] + t_ * (ny_ - Vy[i]);
    if (active && (in_cur != in_nxt)) { if (pos < 16) { ox[pos] = ix; oy[pos] = iy; } pos++; }
    if (active && in_nxt)             { if (pos < 16) { ox[pos] = nx_; oy[pos] = ny_; } pos++; }
  }
  for (int t = 0; t < 16; t++) { Vx[t] = ox[t]; Vy[t] = oy[t]; }
  return pos;
}

__device__ void per_point(const float* gt8, const float* p18, float* gl_out, float* oob_out) {
  float Gx[4], Gy[4];
  for (int i = 0; i < 4; i++) { Gx[i] = gt8[2 * i]; Gy[i] = gt8[2 * i + 1]; }
  float Px[9], Py[9];
  for (int i = 0; i < 9; i++) { Px[i] = p18[2 * i]; Py[i] = p18[2 * i + 1]; }

  // _order_ccw(gt4)
  float cenx = (((Gx[0] + Gx[1]) + Gx[2]) + Gx[3]) / 4.f;
  float ceny = (((Gy[0] + Gy[1]) + Gy[2]) + Gy[3]) / 4.f;
  float ang[4];
  for (int i = 0; i < 4; i++) ang[i] = atan2f(Gy[i] - ceny, Gx[i] - cenx);
  int og[4];
  stable_argsort(ang, 4, og);
  float gx[4], gy[4];
  for (int i = 0; i < 4; i++) { gx[i] = Gx[og[i]]; gy[i] = Gy[og[i]]; }

  // hull of p9 -> a_pred
  float Vx[16], Vy[16];
  int cp = convex_hull(Px, Py, 9, Vx, Vy);
  float a_pred = shoelace16(Vx, Vy, cp);

  // a_gt
  float Tx[16], Ty[16];
  for (int t = 0; t < 16; t++) { Tx[t] = 0.f; Ty[t] = 0.f; }
  for (int i = 0; i < 4; i++) { Tx[i] = gx[i]; Ty[i] = gy[i]; }
  float a_gt = shoelace16(Tx, Ty, 4);

  // clip hull by gt quad
  int c = cp;
  for (int e = 0; e < 4; e++)
    c = clip16(Vx, Vy, c, gx[e], gy[e], gx[(e + 1) & 3], gy[(e + 1) & 3]);
  float a_int = shoelace16(Vx, Vy, c);

  float uni = a_pred + a_gt - a_int;
  float iou = a_int / (uni + 1e-16f);

  // hull of concat([gt4_original, p9])
  float Hx[13], Hy[13];
  for (int i = 0; i < 4; i++) { Hx[i] = Gx[i]; Hy[i] = Gy[i]; }
  for (int i = 0; i < 9; i++) { Hx[4 + i] = Px[i]; Hy[4 + i] = Py[i]; }
  float Wx[16], Wy[16];
  int ch = convex_hull(Hx, Hy, 13, Wx, Wy);
  float a_hull = shoelace16(Wx, Wy, ch);
  float giou = iou - (a_hull - uni) / (a_hull + 1e-16f);
  *gl_out = 1.f - giou;

  // oob
  float acc = 0.f;
  for (int p = 0; p < 9; p++) {
    float mx = -INFINITY;
    for (int e = 0; e < 4; e++) {
      int e1 = (e + 1) & 3;
      float e2x = gx[e1] - gx[e], e2y = gy[e1] - gy[e];
      float nrm = sqrtf(e2x * e2x + e2y * e2y) + 1e-9f;
      float s = (e2x * (Py[p] - gy[e]) - e2y * (Px[p] - gx[e])) / nrm;
      mx = fmaxf(mx, -s);
    }
    acc += fmaxf(mx, 0.f);
  }
  *oob_out = acc / 9.f;
}

__global__ void k_perpoint(const float* __restrict__ rpi, const float* __restrict__ rpr,
                           const float* __restrict__ gob, WS* ws) {
  int t = threadIdx.x;
  int a = t >> 6, p = t & 63;
  if (a > 1) return;
  if (p >= ws->pos_cnt[a]) return;
  int j = ws->pos_j[a][p];
  int g = ws->pos_g[a][p];
  const float* rep = a ? rpr : rpi;
  float gl, oob;
  per_point(gob + (size_t)g * 8, rep + (size_t)j * 18, &gl, &oob);
  atomicAdd(&ws->sums[1 + a * 2], (double)gl);
  atomicAdd(&ws->sums[2 + a * 2], (double)oob);
}

// ---------------- final combine (OUTPUT IS FLOAT32) ----------------
__global__ void k_final(float* out, int N, WS* ws) {
  if (threadIdx.x != 0 || blockIdx.x != 0) return;
  double cls_loss = ws->sums[0] / (double)N;
  double n0 = (double)(ws->pos_cnt[0] > 1 ? ws->pos_cnt[0] : 1);
  double n1 = (double)(ws->pos_cnt[1] > 1 ? ws->pos_cnt[1] : 1);
  double loc_i = ws->sums[1] / n0, sc_i = ws->sums[2] / n0;
  double loc_r = ws->sums[3] / n1, sc_r = ws->sums[4] / n1;
  out[0] = (float)(cls_loss + 0.3 * loc_i + 1.0 * loc_r + 0.05 * sc_i + 0.1 * sc_r);
}

extern "C" void kernel_launch(void* const* d_in, const int* in_sizes, int n_in,
                              void* d_out, int out_size, void* d_ws, size_t ws_size,
                              hipStream_t stream) {
  const float* rpi = (const float*)d_in[0];
  const float* rpr = (const float*)d_in[1];
  const float* cls = (const float*)d_in[2];
  const float* pstride = (const float*)d_in[3];
  const float* gob = (const float*)d_in[4];
  const int* glab = (const int*)d_in[5];
  int N = in_sizes[3];
  int K = in_sizes[5];
  if (K > 64) K = 64;
  WS* ws = (WS*)d_ws;

  int nb = (N + 255) / 256;
  k_init<<<1, 256, 0, stream>>>(ws);
  k_bounds<<<nb, 256, 0, stream>>>(pstride, N, ws);
  k_gtprep<<<1, 64, 0, stream>>>(gob, K, ws);
  k_argmin<<<2 * K * SUB, 256, 0, stream>>>(rpi, rpr, pstride, N, K, ws);
  k_cls<<<nb, 256, 0, stream>>>(cls, N, ws);
  k_resolve<<<1, 1, 0, stream>>>(cls, glab, N, K, ws);
  k_perpoint<<<1, 128, 0, stream>>>(rpi, rpr, gob, ws);
  k_final<<<1, 1, 0, stream>>>((float*)d_out, N, ws);
}

// Round 4
// 208.556 us; speedup vs baseline: 3.2780x; 3.2780x over previous
//
#include <hip/hip_runtime.h>
#include <math.h>
#include <stdint.h>

// Match numpy float32 semantics exactly in branchy geometry (no FMA contraction).
#pragma clang fp contract(off)

#define SUB 16   // sub-blocks per (stage,gt) in argmin

struct WS {
  double sums[8];                  // 0 cls, 1 gl_i, 2 oob_i, 3 gl_r, 4 oob_r
  unsigned long long packed[128];  // (dd_bits<<32)|idx per (a*64+k)
  int lo[8], hi[8];                // per-level [start,end) point ranges
  float gcx[64], gcy[64], gw[64], gh[64];
  int glvl[64];
  int pos_cnt[2];
  int pos_j[2][64];
  int pos_g[2][64];
};

// ---------------- init ----------------
__global__ void k_init(WS* ws) {
  int t = threadIdx.x;
  if (t < 8) { ws->sums[t] = 0.0; ws->lo[t] = 0x7fffffff; ws->hi[t] = 0; }
  if (t < 128) ws->packed[t] = ~0ULL;
  if (t < 2) ws->pos_cnt[t] = 0;
}

// ---------------- per-level index bounds ----------------
__global__ void k_bounds(const float* __restrict__ stridev, int N, WS* ws) {
  __shared__ int slo[8], shi[8];
  int t = threadIdx.x;
  if (t < 8) { slo[t] = 0x7fffffff; shi[t] = 0; }
  __syncthreads();
  int i = blockIdx.x * blockDim.x + t;
  if (i < N) {
    int l = (int)log2f(stridev[i]);
    l = l < 0 ? 0 : (l > 7 ? 7 : l);
    atomicMin(&slo[l], i);
    atomicMax(&shi[l], i + 1);
  }
  __syncthreads();
  if (t < 8 && shi[t] > 0) {
    atomicMin(&ws->lo[t], slo[t]);
    atomicMax(&ws->hi[t], shi[t]);
  }
}

// ---------------- gt preprocessing ----------------
__global__ void k_gtprep(const float* __restrict__ gob, int K, WS* ws) {
  __shared__ int lmin, lmax;
  int k = threadIdx.x;
  if (k == 0) {
    int a = 7, b = 0;
    for (int l = 0; l < 8; l++)
      if (ws->lo[l] < ws->hi[l]) { if (l < a) a = l; if (l > b) b = l; }
    lmin = a; lmax = b;
  }
  __syncthreads();
  if (k < K && k < 64) {
    const float* g = gob + k * 8;
    float x0 = g[0], x1 = g[2], x2 = g[4], x3 = g[6];
    float y0 = g[1], y1 = g[3], y2 = g[5], y3 = g[7];
    float xmin = fminf(fminf(x0, x1), fminf(x2, x3));
    float xmax = fmaxf(fmaxf(x0, x1), fmaxf(x2, x3));
    float ymin = fminf(fminf(y0, y1), fminf(y2, y3));
    float ymax = fmaxf(fmaxf(y0, y1), fmaxf(y2, y3));
    float w = fmaxf(xmax - xmin, 1e-6f);
    float h = fmaxf(ymax - ymin, 1e-6f);
    ws->gcx[k] = (xmin + xmax) * 0.5f;
    ws->gcy[k] = (ymin + ymax) * 0.5f;
    ws->gw[k] = w; ws->gh[k] = h;
    int gl = (int)((log2f(w * 0.25f) + log2f(h * 0.25f)) * 0.5f);  // trunc (positive)
    gl = gl < lmin ? lmin : (gl > lmax ? lmax : gl);
    ws->glvl[k] = gl;
  }
}

// ---------------- per-(stage,gt) argmin ----------------
__global__ void __launch_bounds__(256) k_argmin(const float* __restrict__ rpi,
                                                const float* __restrict__ rpr,
                                                const float* __restrict__ stridev,
                                                int N, int K, WS* ws) {
  int b = blockIdx.x;
  int s = b % SUB;
  int ak = b / SUB;
  int a = ak / K;
  int k = ak % K;
  int L = ws->glvl[k];
  int lo = ws->lo[L], hi = ws->hi[L];
  float cx = ws->gcx[k], cy = ws->gcy[k], w = ws->gw[k], h = ws->gh[k];
  const float* rep = a ? rpr : rpi;
  unsigned long long best = ~0ULL;
  for (int i = lo + s * 256 + (int)threadIdx.x; i < hi; i += SUB * 256) {
    int l = (int)log2f(stridev[i]);
    if (l != L) continue;
    const float2 p = *(const float2*)(rep + (size_t)i * 18 + 8);
    float dx = (p.x - cx) / w, dy = (p.y - cy) / h;
    float dd = sqrtf(dx * dx + dy * dy);
    unsigned long long pk = ((unsigned long long)__float_as_uint(dd) << 32) | (unsigned)i;
    if (pk < best) best = pk;
  }
  __shared__ unsigned long long sb[256];
  sb[threadIdx.x] = best;
  __syncthreads();
  for (int off = 128; off > 0; off >>= 1) {
    if ((int)threadIdx.x < off) {
      unsigned long long o = sb[threadIdx.x + off];
      if (o < sb[threadIdx.x]) sb[threadIdx.x] = o;
    }
    __syncthreads();
  }
  if (threadIdx.x == 0) atomicMin(&ws->packed[a * 64 + k], sb[0]);
}

// ---------------- cls base loss: sum_i (lse_i - x_i[0]) ----------------
__global__ void __launch_bounds__(256) k_cls(const float* __restrict__ cls, int N, WS* ws) {
  __shared__ double sd[256];
  int t = threadIdx.x;
  int i = blockIdx.x * 256 + t;
  double v = 0.0;
  if (i < N) {
    const float4* r = (const float4*)(cls + (size_t)i * 16);
    float4 q0 = r[0], q1 = r[1], q2 = r[2], q3 = r[3];
    float x[16] = {q0.x, q0.y, q0.z, q0.w, q1.x, q1.y, q1.z, q1.w,
                   q2.x, q2.y, q2.z, q2.w, q3.x, q3.y, q3.z, q3.w};
    float m = x[0];
    for (int j = 1; j < 16; j++) m = fmaxf(m, x[j]);
    float ssum = 0.f;
    for (int j = 0; j < 16; j++) ssum += expf(x[j] - m);
    v = (double)(logf(ssum) + m - x[0]);
  }
  sd[t] = v;
  __syncthreads();
  for (int off = 128; off > 0; off >>= 1) {
    if (t < off) sd[t] += sd[t + off];
    __syncthreads();
  }
  if (t == 0) atomicAdd(&ws->sums[0], sd[0]);
}

// ---------------- PARALLEL resolution (replaces 466us serial-scratch kernel) ----
// Sequential-scan semantics: final winner for point j = argmin over (md, k)
// lexicographic (later k overwrites only on strictly smaller md).
__global__ void __launch_bounds__(128) k_resolve_par(const float* __restrict__ cls,
                                                     const int* __restrict__ glab, WS* ws) {
  __shared__ int sj[128];
  __shared__ unsigned long long smdk[128];
  __shared__ int scnt[2];
  int t = threadIdx.x;
  int a = t >> 6, k = t & 63;
  if (t < 2) scnt[t] = 0;
  unsigned long long p = ws->packed[t];
  bool valid = (p != ~0ULL);
  sj[t] = valid ? (int)(unsigned)(p & 0xffffffffu) : (-1 - t);  // unique negatives: no false match
  smdk[t] = (p & 0xffffffff00000000ULL) | (unsigned)k;          // (md_bits, k) lexicographic key
  __syncthreads();
  if (valid) {
    int j = sj[t];
    unsigned long long me = smdk[t];
    bool win = true;
    for (int o = 0; o < 64; o++) {
      int idx = (a << 6) + o;
      if (sj[idx] == j && smdk[idx] < me) win = false;
    }
    if (win) {
      int pos = atomicAdd(&scnt[a], 1);
      ws->pos_j[a][pos] = j;
      ws->pos_g[a][pos] = k;
      if (a == 1) {  // cls correction: x[0] - x[lab] for refine-stage positives
        int lab = glab[k];
        double corr = (double)cls[(size_t)j * 16] - (double)cls[(size_t)j * 16 + lab];
        atomicAdd(&ws->sums[0], corr);
      }
    }
  }
  __syncthreads();
  if (t < 2) ws->pos_cnt[t] = scnt[t];
}

// ---------------- per-point geometry (LDS-backed, no scratch) ----------------
// All dynamically-indexed arrays live in LDS. Stable argsort replaced by
// stable-rank + LDS scatter (identical ordering).
__device__ int hull_lds(int n, float* Px, float* Py, float* Vx, float* Vy, float* Key) {
  unsigned hm = 0; int cnt = 0;
  for (int i = 0; i < n; i++) {
    float pix = Px[i], piy = Py[i];
    bool h = false;
    for (int jj = 0; jj < n && !h; jj++) {
      if (jj == i) continue;
      float dx = Px[jj] - pix, dy = Py[jj] - piy;
      float m = INFINITY;
      #pragma unroll 4
      for (int kk = 0; kk < n; kk++) {
        float cr = dx * (Py[kk] - piy) - dy * (Px[kk] - pix);
        m = fminf(m, cr);
      }
      h = (m >= -1e-6f);
    }
    if (h) { hm |= 1u << i; cnt++; }
  }
  float cenx = 0.f, ceny = 0.f;
  for (int i = 0; i < n; i++) if ((hm >> i) & 1) { cenx += Px[i]; ceny += Py[i]; }
  float dn = (float)(cnt > 1 ? cnt : 1);
  cenx /= dn; ceny /= dn;
  for (int i = 0; i < n; i++)
    Key[i] = ((hm >> i) & 1) ? atan2f(Py[i] - ceny, Px[i] - cenx) : INFINITY;
  for (int t = 0; t < 16; t++) { Vx[t] = 0.f; Vy[t] = 0.f; }
  for (int i = 0; i < n; i++) {
    float ki = Key[i];
    int r = 0;
    for (int jj = 0; jj < n; jj++) {
      float kj = Key[jj];
      r += (int)((kj < ki) || (kj == ki && jj < i));
    }
    Vx[r] = Px[i]; Vy[r] = Py[i];
  }
  return cnt;
}

__device__ float shoelace_lds(const float* Vx, const float* Vy, int c) {
  float s = 0.f;
  for (int i = 0; i < 16; i++) {
    if (i < c) {
      int nx = (i + 1 < c) ? i + 1 : 0;
      s += Vx[i] * Vy[nx] - Vx[nx] * Vy[i];
    }
  }
  return 0.5f * fabsf(s);
}

__device__ int clip_lds(const float* Sx, const float* Sy, float* Dx, float* Dy, int c,
                        float ax, float ay, float bx, float by) {
  float ex = bx - ax, ey = by - ay;
  for (int t = 0; t < 16; t++) { Dx[t] = 0.f; Dy[t] = 0.f; }
  int pos = 0;
  for (int i = 0; i < 16; i++) {
    if (i >= c) continue;
    int nxt = (i + 1 < c) ? i + 1 : 0;
    float cxv = Sx[i], cyv = Sy[i];
    float nxv = Sx[nxt], nyv = Sy[nxt];
    float s_cur = ex * (cyv - ay) - ey * (cxv - ax);
    float s_nxt = ex * (nyv - ay) - ey * (nxv - ax);
    bool in_cur = s_cur >= 0.f, in_nxt = s_nxt >= 0.f;
    float den = s_cur - s_nxt;
    bool safe = fabsf(den) > 1e-9f;
    float tt = safe ? s_cur / den : 0.f;
    if (in_cur != in_nxt) {
      if (pos < 16) { Dx[pos] = cxv + tt * (nxv - cxv); Dy[pos] = cyv + tt * (nyv - cyv); }
      pos++;
    }
    if (in_nxt) {
      if (pos < 16) { Dx[pos] = nxv; Dy[pos] = nyv; }
      pos++;
    }
  }
  return pos;
}

// one positive per block (own CU): lane 0 runs the geometry with block-private LDS
__global__ void __launch_bounds__(64) k_perpoint2(const float* __restrict__ rpi,
                                                  const float* __restrict__ rpr,
                                                  const float* __restrict__ gob, WS* ws) {
  __shared__ float PX[16], PY[16], VX[16], VY[16], OX[16], OY[16], KEY[16];
  int b = blockIdx.x;
  int a = b >> 6, p = b & 63;
  if (p >= ws->pos_cnt[a]) return;
  if (threadIdx.x != 0) return;
  int j = ws->pos_j[a][p];
  int g = ws->pos_g[a][p];
  const float* rep = (a ? rpr : rpi) + (size_t)j * 18;
  const float* gt8 = gob + (size_t)g * 8;

  float Gx[4], Gy[4], Px9[9], Py9[9];
  for (int i = 0; i < 4; i++) { Gx[i] = gt8[2 * i]; Gy[i] = gt8[2 * i + 1]; }
  for (int i = 0; i < 9; i++) { Px9[i] = rep[2 * i]; Py9[i] = rep[2 * i + 1]; }

  // _order_ccw(gt4): static rank-based stable sort (n=4, fully unrolled)
  float cenx = (((Gx[0] + Gx[1]) + Gx[2]) + Gx[3]) / 4.f;
  float ceny = (((Gy[0] + Gy[1]) + Gy[2]) + Gy[3]) / 4.f;
  float ang[4];
  for (int i = 0; i < 4; i++) ang[i] = atan2f(Gy[i] - ceny, Gx[i] - cenx);
  int r4[4];
  for (int i = 0; i < 4; i++) {
    int r = 0;
    for (int jj = 0; jj < 4; jj++)
      r += (int)((ang[jj] < ang[i]) || (ang[jj] == ang[i] && jj < i));
    r4[i] = r;
  }
  float gx[4], gy[4];
  for (int d = 0; d < 4; d++) {
    float sx = 0.f, sy = 0.f;
    for (int i = 0; i < 4; i++) if (r4[i] == d) { sx = Gx[i]; sy = Gy[i]; }
    gx[d] = sx; gy[d] = sy;
  }

  // hull of p9 -> a_pred
  for (int i = 0; i < 9; i++) { PX[i] = Px9[i]; PY[i] = Py9[i]; }
  int cp = hull_lds(9, PX, PY, VX, VY, KEY);
  float a_pred = shoelace_lds(VX, VY, cp);

  // a_gt (quad shoelace, static)
  float sgt = 0.f;
  for (int i = 0; i < 4; i++) {
    int nx = (i + 1) & 3;
    sgt += gx[i] * gy[nx] - gx[nx] * gy[i];
  }
  float a_gt = 0.5f * fabsf(sgt);

  // clip hull by gt quad (ping-pong V <-> O)
  int c = cp;
  c = clip_lds(VX, VY, OX, OY, c, gx[0], gy[0], gx[1], gy[1]);
  c = clip_lds(OX, OY, VX, VY, c, gx[1], gy[1], gx[2], gy[2]);
  c = clip_lds(VX, VY, OX, OY, c, gx[2], gy[2], gx[3], gy[3]);
  c = clip_lds(OX, OY, VX, VY, c, gx[3], gy[3], gx[0], gy[0]);
  float a_int = shoelace_lds(VX, VY, c);

  float uni = a_pred + a_gt - a_int;
  float iou = a_int / (uni + 1e-16f);

  // hull of concat([gt4_original, p9])
  for (int i = 0; i < 4; i++) { PX[i] = Gx[i]; PY[i] = Gy[i]; }
  for (int i = 0; i < 9; i++) { PX[4 + i] = Px9[i]; PY[4 + i] = Py9[i]; }
  int ch = hull_lds(13, PX, PY, VX, VY, KEY);
  float a_hull = shoelace_lds(VX, VY, ch);
  float giou = iou - (a_hull - uni) / (a_hull + 1e-16f);
  float gl = 1.f - giou;

  // oob (static register loops)
  float acc = 0.f;
  for (int pp = 0; pp < 9; pp++) {
    float mx = -INFINITY;
    for (int e = 0; e < 4; e++) {
      int e1 = (e + 1) & 3;
      float e2x = gx[e1] - gx[e], e2y = gy[e1] - gy[e];
      float nrm = sqrtf(e2x * e2x + e2y * e2y) + 1e-9f;
      float s = (e2x * (Py9[pp] - gy[e]) - e2y * (Px9[pp] - gx[e])) / nrm;
      mx = fmaxf(mx, -s);
    }
    acc += fmaxf(mx, 0.f);
  }
  float oob = acc / 9.f;

  atomicAdd(&ws->sums[1 + a * 2], (double)gl);
  atomicAdd(&ws->sums[2 + a * 2], (double)oob);
}

// ---------------- final combine (f32 output) ----------------
__global__ void k_final(float* out, int N, WS* ws) {
  if (threadIdx.x != 0 || blockIdx.x != 0) return;
  double cls_loss = ws->sums[0] / (double)N;
  double n0 = (double)(ws->pos_cnt[0] > 1 ? ws->pos_cnt[0] : 1);
  double n1 = (double)(ws->pos_cnt[1] > 1 ? ws->pos_cnt[1] : 1);
  double loc_i = ws->sums[1] / n0, sc_i = ws->sums[2] / n0;
  double loc_r = ws->sums[3] / n1, sc_r = ws->sums[4] / n1;
  out[0] = (float)(cls_loss + 0.3 * loc_i + 1.0 * loc_r + 0.05 * sc_i + 0.1 * sc_r);
}

extern "C" void kernel_launch(void* const* d_in, const int* in_sizes, int n_in,
                              void* d_out, int out_size, void* d_ws, size_t ws_size,
                              hipStream_t stream) {
  const float* rpi = (const float*)d_in[0];
  const float* rpr = (const float*)d_in[1];
  const float* cls = (const float*)d_in[2];
  const float* pstride = (const float*)d_in[3];
  const float* gob = (const float*)d_in[4];
  const int* glab = (const int*)d_in[5];
  int N = in_sizes[3];
  int K = in_sizes[5];
  if (K > 64) K = 64;
  WS* ws = (WS*)d_ws;

  int nb = (N + 255) / 256;
  k_init<<<1, 256, 0, stream>>>(ws);
  k_bounds<<<nb, 256, 0, stream>>>(pstride, N, ws);
  k_gtprep<<<1, 64, 0, stream>>>(gob, K, ws);
  k_argmin<<<2 * K * SUB, 256, 0, stream>>>(rpi, rpr, pstride, N, K, ws);
  k_cls<<<nb, 256, 0, stream>>>(cls, N, ws);
  k_resolve_par<<<1, 128, 0, stream>>>(cls, glab, ws);
  k_perpoint2<<<128, 64, 0, stream>>>(rpi, rpr, gob, ws);
  k_final<<<1, 1, 0, stream>>>((float*)d_out, N, ws);
}

// Round 5
// 104.381 us; speedup vs baseline: 6.5496x; 1.9980x over previous
//
#include <hip/hip_runtime.h>
#include <math.h>
#include <stdint.h>

// Match numpy float32 semantics exactly in branchy geometry (no FMA contraction).
#pragma clang fp contract(off)

#define SUB 16   // sub-blocks per (stage,gt) in argmin

struct WS {
  double sums[8];                  // 0 cls, 1 gl_i, 2 oob_i, 3 gl_r, 4 oob_r
  unsigned long long packed[128];  // (dd_bits<<32)|idx per (a*64+k)
  int lo[8], hi[8];                // per-level [start,end) point ranges
  float gcx[64], gcy[64], gw[64], gh[64];
  int glvl[64];
  unsigned cntpub[2];              // published positive counts (intra-kernel coherent)
  unsigned done2;                  // k_post completion counter
};

// ============ k_pre: init + level bounds (binary search; stridev sorted) + gtprep ============
__global__ void k_pre(const float* __restrict__ stridev, const float* __restrict__ gob,
                      int N, int K, WS* ws) {
  __shared__ int bnd[9];
  __shared__ int slmin, slmax;
  int t = threadIdx.x;
  if (t < 8) ws->sums[t] = 0.0;
  if (t < 128) ws->packed[t] = ~0ULL;
  if (t == 0) { ws->done2 = 0u; ws->cntpub[0] = 0u; ws->cntpub[1] = 0u; }
  if (t < 9) {  // lower_bound of 2^t in sorted stride array
    float v = (float)(1 << t);
    int lo = 0, hi = N;
    while (lo < hi) { int mid = (lo + hi) >> 1; if (stridev[mid] < v) lo = mid + 1; else hi = mid; }
    bnd[t] = lo;
  }
  __syncthreads();
  if (t == 0) {
    int a = 7, b = 0;
    for (int l = 0; l < 8; l++) {
      int lo = bnd[l], hi = bnd[l + 1];
      ws->lo[l] = lo; ws->hi[l] = hi;
      if (hi > lo) { if (l < a) a = l; if (l > b) b = l; }
    }
    slmin = a; slmax = b;
  }
  __syncthreads();
  if (t < K && t < 64) {
    const float* g = gob + t * 8;
    float x0 = g[0], x1 = g[2], x2 = g[4], x3 = g[6];
    float y0 = g[1], y1 = g[3], y2 = g[5], y3 = g[7];
    float xmin = fminf(fminf(x0, x1), fminf(x2, x3));
    float xmax = fmaxf(fmaxf(x0, x1), fmaxf(x2, x3));
    float ymin = fminf(fminf(y0, y1), fminf(y2, y3));
    float ymax = fmaxf(fmaxf(y0, y1), fmaxf(y2, y3));
    float w = fmaxf(xmax - xmin, 1e-6f);
    float h = fmaxf(ymax - ymin, 1e-6f);
    ws->gcx[t] = (xmin + xmax) * 0.5f;
    ws->gcy[t] = (ymin + ymax) * 0.5f;
    ws->gw[t] = w; ws->gh[t] = h;
    int gl = (int)((log2f(w * 0.25f) + log2f(h * 0.25f)) * 0.5f);  // trunc (positive)
    gl = gl < slmin ? slmin : (gl > slmax ? slmax : gl);
    ws->glvl[t] = gl;
  }
}

// ============ k_main: argmin blocks [0,AB) + cls blocks [AB, AB+nb) ============
__global__ void __launch_bounds__(256) k_main(const float* __restrict__ rpi,
                                              const float* __restrict__ rpr,
                                              const float* __restrict__ cls,
                                              int N, int K, int AB, WS* ws) {
  __shared__ unsigned long long sb[256];
  int t = threadIdx.x;
  int b = blockIdx.x;
  if (b < AB) {
    int s = b % SUB;
    int ak = b / SUB;
    int a = ak / K;
    int k = ak % K;
    int L = ws->glvl[k];
    int lo = ws->lo[L], hi = ws->hi[L];
    float cx = ws->gcx[k], cy = ws->gcy[k], w = ws->gw[k], h = ws->gh[k];
    const float* rep = a ? rpr : rpi;
    unsigned long long best = ~0ULL;
    for (int i = lo + s * 256 + t; i < hi; i += SUB * 256) {
      const float2 p = *(const float2*)(rep + (size_t)i * 18 + 8);
      float dx = (p.x - cx) / w, dy = (p.y - cy) / h;
      float dd = sqrtf(dx * dx + dy * dy);
      unsigned long long pk = ((unsigned long long)__float_as_uint(dd) << 32) | (unsigned)i;
      if (pk < best) best = pk;
    }
    sb[t] = best;
    __syncthreads();
    for (int off = 128; off > 0; off >>= 1) {
      if (t < off) { unsigned long long o = sb[t + off]; if (o < sb[t]) sb[t] = o; }
      __syncthreads();
    }
    if (t == 0) atomicMin(&ws->packed[a * 64 + k], sb[0]);
  } else {
    int i = (b - AB) * 256 + t;
    double v = 0.0;
    if (i < N) {
      const float4* r = (const float4*)(cls + (size_t)i * 16);
      float4 q0 = r[0], q1 = r[1], q2 = r[2], q3 = r[3];
      float x[16] = {q0.x, q0.y, q0.z, q0.w, q1.x, q1.y, q1.z, q1.w,
                     q2.x, q2.y, q2.z, q2.w, q3.x, q3.y, q3.z, q3.w};
      float m = x[0];
      for (int j = 1; j < 16; j++) m = fmaxf(m, x[j]);
      float ssum = 0.f;
      for (int j = 0; j < 16; j++) ssum += expf(x[j] - m);
      v = (double)(logf(ssum) + m - x[0]);
    }
    double* sd = (double*)sb;
    sd[t] = v;
    __syncthreads();
    for (int off = 128; off > 0; off >>= 1) {
      if (t < off) sd[t] += sd[t + off];
      __syncthreads();
    }
    if (t == 0) atomicAdd(&ws->sums[0], sd[0]);
  }
}

// ============ wave-parallel geometry helpers (block = 1 wave of 64) ============

// shoelace over first c of 16 LDS verts — all lanes compute identically (serial ref order)
__device__ __forceinline__ float shoe(const float* VX, const float* VY, int c) {
  float s = 0.f;
  #pragma unroll
  for (int i = 0; i < 16; i++) {
    if (i < c) {
      int nx = (i + 1 < c) ? ((i + 1 < 16) ? i + 1 : 15) : 0;  // JAX OOB-gather clamp
      s += VX[i] * VY[nx] - VX[nx] * VY[i];
    }
  }
  return 0.5f * fabsf(s);
}

// one Sutherland-Hodgman edge, wave-parallel; exact interleaved-cumsum positions via ballots
__device__ __forceinline__ int clip_edge(const float* SX, const float* SY, float* DX, float* DY,
                                         int c, float ax, float ay, float bx, float by, int lane) {
  if (lane < 16) { DX[lane] = 0.f; DY[lane] = 0.f; }
  bool f_int = false, f_nxt = false;
  float ix = 0.f, iy = 0.f, nxv = 0.f, nyv = 0.f;
  if (lane < 16 && lane < c) {
    int nxt = (lane + 1 < c) ? lane + 1 : 0;
    if (nxt > 15) nxt = 15;
    float cxv = SX[lane], cyv = SY[lane];
    nxv = SX[nxt]; nyv = SY[nxt];
    float ex = bx - ax, ey = by - ay;
    float s_cur = ex * (cyv - ay) - ey * (cxv - ax);
    float s_nxt = ex * (nyv - ay) - ey * (nxv - ax);
    bool in_cur = s_cur >= 0.f, in_nxt = s_nxt >= 0.f;
    float den = s_cur - s_nxt;
    bool safe = fabsf(den) > 1e-9f;
    float tt = safe ? s_cur / den : 0.f;
    ix = cxv + tt * (nxv - cxv);
    iy = cyv + tt * (nyv - cyv);
    f_int = (in_cur != in_nxt);
    f_nxt = in_nxt;
  }
  unsigned long long bi = __ballot(f_int), bn = __ballot(f_nxt);
  unsigned long long lt = (1ULL << lane) - 1ULL;
  int below = __popcll(bi & lt) + __popcll(bn & lt);
  if (f_int && below < 16) { DX[below] = ix; DY[below] = iy; }
  int posn = below + (f_int ? 1 : 0);
  if (f_nxt && posn < 16) { DX[posn] = nxv; DY[posn] = nyv; }
  __syncthreads();
  return __popcll(bi) + __popcll(bn);
}

// O(n^3) hull, pairs over lanes; sorted verts (stable-rank == jnp stable argsort) into VX/VY
template <int NP>
__device__ __forceinline__ int hull_wave(const float* PX, const float* PY, int base,
                                         float* VX, float* VY, float* KEY, int lane) {
  constexpr int TOT = NP * NP;
  unsigned long long B0 = 0, B1 = 0, B2 = 0;
  {
    bool h = false;
    int idx = lane;
    if (idx < TOT) {
      int i = idx / NP, j = idx % NP;
      if (i != j) {
        float pix = PX[base + i], piy = PY[base + i];
        float dx = PX[base + j] - pix, dy = PY[base + j] - piy;
        float m = INFINITY;
        #pragma unroll
        for (int k = 0; k < NP; k++)
          m = fminf(m, dx * (PY[base + k] - piy) - dy * (PX[base + k] - pix));
        h = (m >= -1e-6f);
      }
    }
    B0 = __ballot(h);
  }
  if constexpr (TOT > 64) {
    bool h = false;
    int idx = lane + 64;
    if (idx < TOT) {
      int i = idx / NP, j = idx % NP;
      if (i != j) {
        float pix = PX[base + i], piy = PY[base + i];
        float dx = PX[base + j] - pix, dy = PY[base + j] - piy;
        float m = INFINITY;
        #pragma unroll
        for (int k = 0; k < NP; k++)
          m = fminf(m, dx * (PY[base + k] - piy) - dy * (PX[base + k] - pix));
        h = (m >= -1e-6f);
      }
    }
    B1 = __ballot(h);
  }
  if constexpr (TOT > 128) {
    bool h = false;
    int idx = lane + 128;
    if (idx < TOT) {
      int i = idx / NP, j = idx % NP;
      if (i != j) {
        float pix = PX[base + i], piy = PY[base + i];
        float dx = PX[base + j] - pix, dy = PY[base + j] - piy;
        float m = INFINITY;
        #pragma unroll
        for (int k = 0; k < NP; k++)
          m = fminf(m, dx * (PY[base + k] - piy) - dy * (PX[base + k] - pix));
        h = (m >= -1e-6f);
      }
    }
    B2 = __ballot(h);
  }
  // per-point hull membership: OR of row i's NP bits
  bool hull_i = false;
  if (lane < NP) {
    int s = lane * NP, w = s >> 6, off = s & 63;
    unsigned long long Bw = (w == 0) ? B0 : ((w == 1) ? B1 : B2);
    unsigned long long Bw1 = (w == 0) ? B1 : ((w == 1) ? B2 : 0ULL);
    unsigned long long bits = Bw >> off;
    if (off) bits |= Bw1 << (64 - off);
    hull_i = (bits & ((1ULL << NP) - 1ULL)) != 0ULL;
  }
  unsigned long long hmask = __ballot(hull_i);
  int cnt = __popcll(hmask);
  // centroid over hull points, reference (ascending-index) order; uniform on all lanes
  float cx = 0.f, cy = 0.f;
  #pragma unroll
  for (int k = 0; k < NP; k++)
    if ((hmask >> k) & 1ULL) { cx += PX[base + k]; cy += PY[base + k]; }
  float dn = (float)(cnt > 1 ? cnt : 1);
  cx /= dn; cy /= dn;
  if (lane < NP)
    KEY[lane] = hull_i ? atan2f(PY[base + lane] - cy, PX[base + lane] - cx) : INFINITY;
  if (lane < 16) { VX[lane] = 0.f; VY[lane] = 0.f; }
  __syncthreads();
  if (lane < NP) {
    float ki = KEY[lane];
    int r = 0;
    #pragma unroll
    for (int j2 = 0; j2 < NP; j2++) {
      float kj = KEY[j2];
      r += (int)((kj < ki) || (kj == ki && j2 < lane));
    }
    VX[r] = PX[base + lane];
    VY[r] = PY[base + lane];
  }
  __syncthreads();
  return cnt;
}

// ============ k_post: per-block resolve + wave-parallel geometry + last-block final ============
__global__ void __launch_bounds__(64) k_post(const float* __restrict__ rpi,
                                             const float* __restrict__ rpr,
                                             const float* __restrict__ gob,
                                             const int* __restrict__ glab,
                                             const float* __restrict__ cls,
                                             int N, float* out, WS* ws) {
  __shared__ float PXs[16], PYs[16], VX[16], VY[16], DX[16], DY[16], KEY[16], RED[9];
  __shared__ int SJ[64];
  __shared__ unsigned long long SMK[64];
  int lane = threadIdx.x;
  int b = blockIdx.x;
  int a = b >> 6, p = b & 63;

  // ---- redundant per-block resolve (deterministic winner set, k-order enumeration) ----
  unsigned long long pk = ws->packed[a * 64 + lane];  // prev-dispatch write: coherent
  bool valid = (pk != ~0ULL);
  SJ[lane] = valid ? (int)(unsigned)(pk & 0xffffffffu) : (-1 - lane);
  SMK[lane] = (pk & 0xffffffff00000000ULL) | (unsigned)lane;  // (md, k) lexicographic
  __syncthreads();
  bool win = false;
  if (valid) {
    int j = SJ[lane];
    unsigned long long me = SMK[lane];
    win = true;
    for (int o = 0; o < 64; o++)
      if (SJ[o] == j && SMK[o] < me) win = false;
  }
  unsigned long long wmask = __ballot(win);
  int cnt = __popcll(wmask);
  if (p == 0 && lane == 0) atomicExch(&ws->cntpub[a], (unsigned)cnt);

  bool active = (p < cnt);
  if (active) {
    int kk = 0;
    { int c2 = 0;
      for (int o = 0; o < 64; o++)
        if ((wmask >> o) & 1ULL) { if (c2 == p) { kk = o; break; } c2++; } }
    int j = SJ[kk];
    const float* rep = (a ? rpr : rpi) + (size_t)j * 18;
    const float* gt8 = gob + (size_t)kk * 8;
    if (lane < 4) { PXs[lane] = gt8[2 * lane]; PYs[lane] = gt8[2 * lane + 1]; }
    else if (lane < 13) { int q = lane - 4; PXs[lane] = rep[2 * q]; PYs[lane] = rep[2 * q + 1]; }
    __syncthreads();

    // _order_ccw(gt4) — uniform on all lanes, reference serial order
    float cenx = (((PXs[0] + PXs[1]) + PXs[2]) + PXs[3]) / 4.f;
    float ceny = (((PYs[0] + PYs[1]) + PYs[2]) + PYs[3]) / 4.f;
    float angv[4];
    int r4[4];
    #pragma unroll
    for (int i = 0; i < 4; i++) angv[i] = atan2f(PYs[i] - ceny, PXs[i] - cenx);
    #pragma unroll
    for (int i = 0; i < 4; i++) {
      int r = 0;
      #pragma unroll
      for (int j2 = 0; j2 < 4; j2++)
        r += (int)((angv[j2] < angv[i]) || (angv[j2] == angv[i] && j2 < i));
      r4[i] = r;
    }
    float qx[4], qy[4];
    #pragma unroll
    for (int d = 0; d < 4; d++) {
      float sx = 0.f, sy = 0.f;
      #pragma unroll
      for (int i = 0; i < 4; i++) if (r4[i] == d) { sx = PXs[i]; sy = PYs[i]; }
      qx[d] = sx; qy[d] = sy;
    }

    int cp = hull_wave<9>(PXs, PYs, 4, VX, VY, KEY, lane);
    float a_pred = shoe(VX, VY, cp);

    float sgt = 0.f;
    #pragma unroll
    for (int i = 0; i < 4; i++) {
      int nx = (i + 1) & 3;
      sgt += qx[i] * qy[nx] - qx[nx] * qy[i];
    }
    float a_gt = 0.5f * fabsf(sgt);

    int c = cp;
    c = clip_edge(VX, VY, DX, DY, c, qx[0], qy[0], qx[1], qy[1], lane);
    c = clip_edge(DX, DY, VX, VY, c, qx[1], qy[1], qx[2], qy[2], lane);
    c = clip_edge(VX, VY, DX, DY, c, qx[2], qy[2], qx[3], qy[3], lane);
    c = clip_edge(DX, DY, VX, VY, c, qx[3], qy[3], qx[0], qy[0], lane);
    float a_int = shoe(VX, VY, c);

    float uni = a_pred + a_gt - a_int;
    float iou = a_int / (uni + 1e-16f);

    int ch = hull_wave<13>(PXs, PYs, 0, VX, VY, KEY, lane);
    float a_hull = shoe(VX, VY, ch);
    float giou = iou - (a_hull - uni) / (a_hull + 1e-16f);
    float gl = 1.f - giou;

    // oob: 9 points x 4 edges over lanes, exact max, reference-order sum on lane 0
    float mxv = -INFINITY;
    if (lane < 36) {
      int pp = lane >> 2, e = lane & 3;
      float ax = e == 0 ? qx[0] : e == 1 ? qx[1] : e == 2 ? qx[2] : qx[3];
      float ay = e == 0 ? qy[0] : e == 1 ? qy[1] : e == 2 ? qy[2] : qy[3];
      float bx2 = e == 0 ? qx[1] : e == 1 ? qx[2] : e == 2 ? qx[3] : qx[0];
      float by2 = e == 0 ? qy[1] : e == 1 ? qy[2] : e == 2 ? qy[3] : qy[0];
      float ex = bx2 - ax, ey = by2 - ay;
      float nrm = sqrtf(ex * ex + ey * ey) + 1e-9f;
      float px = PXs[4 + pp], py = PYs[4 + pp];
      float s = (ex * (py - ay) - ey * (px - ax)) / nrm;
      mxv = -s;
    }
    float o1 = __shfl_xor(mxv, 1); mxv = fmaxf(mxv, o1);
    float o2 = __shfl_xor(mxv, 2); mxv = fmaxf(mxv, o2);
    if (lane < 36 && (lane & 3) == 0) RED[lane >> 2] = fmaxf(mxv, 0.f);
    __syncthreads();
    if (lane == 0) {
      float acc = 0.f;
      #pragma unroll
      for (int pp = 0; pp < 9; pp++) acc += RED[pp];
      float oob = acc / 9.f;
      atomicAdd(&ws->sums[1 + a * 2], (double)gl);
      atomicAdd(&ws->sums[2 + a * 2], (double)oob);
      if (a == 1) {  // cls correction for refine-stage positives
        int lab = glab[kk];
        double corr = (double)cls[(size_t)j * 16] - (double)cls[(size_t)j * 16 + lab];
        atomicAdd(&ws->sums[0], corr);
      }
    }
  }

  // ---- last-block final combine (device-scope counter + atomic readback) ----
  __syncthreads();
  if (lane == 0) {
    __threadfence();
    unsigned d = atomicAdd(&ws->done2, 1u);
    if (d == gridDim.x - 1) {
      __threadfence();
      double s0 = atomicAdd(&ws->sums[0], 0.0);
      double s1 = atomicAdd(&ws->sums[1], 0.0);
      double s2 = atomicAdd(&ws->sums[2], 0.0);
      double s3 = atomicAdd(&ws->sums[3], 0.0);
      double s4 = atomicAdd(&ws->sums[4], 0.0);
      unsigned c0 = atomicAdd(&ws->cntpub[0], 0u);
      unsigned c1 = atomicAdd(&ws->cntpub[1], 0u);
      double n0 = (double)(c0 > 1u ? c0 : 1u);
      double n1 = (double)(c1 > 1u ? c1 : 1u);
      out[0] = (float)(s0 / (double)N + 0.3 * (s1 / n0) + 1.0 * (s3 / n1) +
                       0.05 * (s2 / n0) + 0.1 * (s4 / n1));
    }
  }
}

extern "C" void kernel_launch(void* const* d_in, const int* in_sizes, int n_in,
                              void* d_out, int out_size, void* d_ws, size_t ws_size,
                              hipStream_t stream) {
  const float* rpi = (const float*)d_in[0];
  const float* rpr = (const float*)d_in[1];
  const float* cls = (const float*)d_in[2];
  const float* pstride = (const float*)d_in[3];
  const float* gob = (const float*)d_in[4];
  const int* glab = (const int*)d_in[5];
  int N = in_sizes[3];
  int K = in_sizes[5];
  if (K > 64) K = 64;
  WS* ws = (WS*)d_ws;

  int AB = 2 * K * SUB;
  int nb = (N + 255) / 256;
  k_pre<<<1, 256, 0, stream>>>(pstride, gob, N, K, ws);
  k_main<<<AB + nb, 256, 0, stream>>>(rpi, rpr, cls, N, K, AB, ws);
  k_post<<<128, 64, 0, stream>>>(rpi, rpr, gob, glab, cls, N, (float*)d_out, ws);
}